// Round 2
// baseline (101.667 us; speedup 1.0000x reference)
//
#include <hip/hip_runtime.h>

#define NIMG 8
#define NC 19
#define HW (512*1024)
#define BPI 256          // blocks per image
#define TPB 256
#define ITERS 2          // float4 chunks/thread: (HW/4)/(BPI*TPB) = 131072/65536
#define OLD_CL 11

// ---------------- main pass: per-pixel softmax^2 per-class sums + argmax hist ----------------
__global__ __launch_bounds__(TPB, 4) void iw_main(const float* __restrict__ in,
                                                  float* __restrict__ sPart,
                                                  unsigned* __restrict__ hPart) {
    const int b   = blockIdx.x;        // 0 .. NIMG*BPI-1
    const int n   = b >> 8;            // image (BPI=256)
    const int bl  = b & (BPI - 1);
    const int tid = threadIdx.x;
    const float* img = in + (size_t)n * NC * HW;

    float    acc[NC];
    unsigned hc[3];                    // 19 counters x 4-bit fields (max 8/thread)
#pragma unroll
    for (int c = 0; c < NC; ++c) acc[c] = 0.f;
    hc[0] = hc[1] = hc[2] = 0u;

    const float L2E  = 1.4426950408889634f;
    const float L2E2 = 2.8853900817779268f;

    for (int it = 0; it < ITERS; ++it) {
        const int    chunk = (bl * TPB + tid) + it * (BPI * TPB);
        const size_t p     = (size_t)chunk * 4;

        float x0[NC], x1[NC], x2[NC], x3[NC];
#pragma unroll
        for (int c = 0; c < NC; ++c) {
            const float4 t = *reinterpret_cast<const float4*>(img + (size_t)c * HW + p);
            x0[c] = t.x; x1[c] = t.y; x2[c] = t.z; x3[c] = t.w;
        }

#define PIXEL(X)                                                              \
        {                                                                     \
            /* max via fmax tree */                                           \
            float m = X[0];                                                   \
            _Pragma("unroll")                                                 \
            for (int c = 1; c < NC; ++c) m = fmaxf(m, X[c]);                  \
            /* first index equal to max (scan high->low keeps lowest) */      \
            int mi = NC - 1;                                                  \
            _Pragma("unroll")                                                 \
            for (int c = NC - 2; c >= 0; --c) mi = (X[c] == m) ? c : mi;      \
            /* packed histogram: reg mi>>3, field (mi&7)*4 */                 \
            {                                                                 \
                const unsigned inc = 1u << ((mi & 7) * 4);                    \
                const int r = mi >> 3;                                        \
                hc[0] += (r == 0) ? inc : 0u;                                 \
                hc[1] += (r == 1) ? inc : 0u;                                 \
                hc[2] += (r == 2) ? inc : 0u;                                 \
            }                                                                 \
            const float ml = m * L2E;                                         \
            float d = 0.f;                                                    \
            _Pragma("unroll")                                                 \
            for (int c = 0; c < NC; ++c)                                      \
                d += exp2f(fmaf(X[c], L2E, -ml));                             \
            /* acc[c] += (e_c/d)^2 = exp2(2*y_c - 2*log2 d) */                \
            const float h = fmaf(-2.f, __log2f(d), -2.f * ml);                \
            _Pragma("unroll")                                                 \
            for (int c = 0; c < NC; ++c)                                      \
                acc[c] += exp2f(fmaf(X[c], L2E2, h));                         \
        }

        PIXEL(x0); PIXEL(x1); PIXEL(x2); PIXEL(x3);
#undef PIXEL
    }

    // ---- unpack hist, wave (64-lane) butterfly reduce ----
    unsigned hu[NC];
#pragma unroll
    for (int c = 0; c < NC; ++c) hu[c] = (hc[c >> 3] >> ((c & 7) * 4)) & 0xFu;

#pragma unroll
    for (int c = 0; c < NC; ++c) {
#pragma unroll
        for (int off = 32; off >= 1; off >>= 1) {
            acc[c] += __shfl_xor(acc[c], off, 64);
            hu[c]  += (unsigned)__shfl_xor((int)hu[c], off, 64);
        }
    }

    // ---- cross-wave combine via LDS (4 waves/block), deterministic ----
    __shared__ float    ls[TPB / 64][NC];
    __shared__ unsigned lh[TPB / 64][NC];
    const int wave = tid >> 6;
    const int lane = tid & 63;
    if (lane == 0) {
#pragma unroll
        for (int c = 0; c < NC; ++c) { ls[wave][c] = acc[c]; lh[wave][c] = hu[c]; }
    }
    __syncthreads();
    if (tid < NC) {
        float s = 0.f; unsigned h = 0u;
#pragma unroll
        for (int w = 0; w < TPB / 64; ++w) { s += ls[w][tid]; h += lh[w][tid]; }
        sPart[(size_t)b * NC + tid] = s;
        hPart[(size_t)b * NC + tid] = h;
    }
}

// ---------------- final reduce: block partials -> hist -> weight -> scalar loss ----------------
__global__ __launch_bounds__(1024) void iw_final(const float* __restrict__ sPart,
                                                 const unsigned* __restrict__ hPart,
                                                 float* __restrict__ out) {
    __shared__ double   ps[NIMG * NC][4];
    __shared__ unsigned ph[NIMG * NC][4];
    __shared__ double contrib[NIMG * NC];
    __shared__ double histL[NIMG * NC];
    __shared__ double hsum[NIMG];
    const int t   = threadIdx.x;
    const int idx = t >> 2;        // (n,c) pair
    const int k   = t & 3;

    if (idx < NIMG * NC) {
        const int n = idx / NC, c = idx % NC;
        double s = 0.0; unsigned h = 0u;
        for (int j = k; j < BPI; j += 4) {
            s += (double)sPart[(size_t)(n * BPI + j) * NC + c];
            h += hPart[(size_t)(n * BPI + j) * NC + c];
        }
        ps[idx][k] = s; ph[idx][k] = h;
    }
    __syncthreads();
    if (t < NIMG * NC) {
        double s = ps[t][0] + ps[t][1] + ps[t][2] + ps[t][3];
        unsigned h = ph[t][0] + ph[t][1] + ph[t][2] + ph[t][3];
        const double H = (h == 0u) ? 1.0 : (double)h;
        histL[t] = H;
        contrib[t] = s;              // temporarily S
    }
    __syncthreads();
    if (t < NIMG) {
        double hs = 0.0;
        for (int c = 0; c < NC; ++c) hs += histL[t * NC + c];
        hsum[t] = hs;
    }
    __syncthreads();
    if (t < NIMG * NC) {
        const int n = t / NC, c = t % NC;
        const double w = (c < OLD_CL) ? 1.0 : pow(hsum[n] / histL[t], 0.2);
        contrib[t] = w * contrib[t];
    }
    __syncthreads();
    if (t == 0) {
        double tot = 0.0;
        for (int i = 0; i < NIMG * NC; ++i) tot += contrib[i];
        out[0] = (float)(-tot / (double)((size_t)NIMG * NC * HW));
    }
}

extern "C" void kernel_launch(void* const* d_in, const int* in_sizes, int n_in,
                              void* d_out, int out_size, void* d_ws, size_t ws_size,
                              hipStream_t stream) {
    const float* in = (const float*)d_in[0];
    float* out = (float*)d_out;

    float*    sPart = (float*)d_ws;
    unsigned* hPart = (unsigned*)((char*)d_ws + (size_t)NIMG * BPI * NC * sizeof(float));

    iw_main<<<dim3(NIMG * BPI), TPB, 0, stream>>>(in, sPart, hPart);
    iw_final<<<1, 1024, 0, stream>>>(sPart, hPart, out);
}

// Round 3
// 72.929 us; speedup vs baseline: 1.3941x; 1.3941x over previous
//
#include <hip/hip_runtime.h>

#define NIMG 8
#define NC 19
#define HW (512*1024)
#define BPI 128          // blocks per image
#define TPB 256
#define ITERS 8          // float2 chunks/thread: (HW/2)/(BPI*TPB) = 262144/32768
#define OLD_CL 11

typedef float f32x2 __attribute__((ext_vector_type(2)));

// ---------------- main pass: per-pixel softmax^2 per-class sums + argmax hist ----------------
__global__ __launch_bounds__(TPB, 4) void iw_main(const float* __restrict__ in,
                                                  float* __restrict__ sPart,
                                                  unsigned* __restrict__ hPart) {
    const int b   = blockIdx.x;        // 0 .. NIMG*BPI-1
    const int n   = b >> 7;            // image (BPI=128)
    const int bl  = b & (BPI - 1);
    const int tid = threadIdx.x;
    const float* img = in + (size_t)n * NC * HW;

    float    acc[NC];
    unsigned hc[5];                    // 19 counters x 8-bit fields (max 16 px/thread)
#pragma unroll
    for (int c = 0; c < NC; ++c) acc[c] = 0.f;
#pragma unroll
    for (int r = 0; r < 5; ++r) hc[r] = 0u;

    const float L2E = 1.4426950408889634f;

    for (int it = 0; it < ITERS; ++it) {
        const int    chunk = (bl * TPB + tid) + it * (BPI * TPB);
        const size_t p     = (size_t)chunk * 2;

        float x0[NC], x1[NC];
#pragma unroll
        for (int c = 0; c < NC; ++c) {
            const f32x2 t = __builtin_nontemporal_load(
                reinterpret_cast<const f32x2*>(img + (size_t)c * HW + p));
            x0[c] = t[0]; x1[c] = t[1];
        }

#define PIXEL(X)                                                              \
        {                                                                     \
            float m = X[0];                                                   \
            _Pragma("unroll")                                                 \
            for (int c = 1; c < NC; ++c) m = fmaxf(m, X[c]);                  \
            int mi = NC - 1;                                                  \
            _Pragma("unroll")                                                 \
            for (int c = NC - 2; c >= 0; --c) mi = (X[c] == m) ? c : mi;      \
            {                                                                 \
                const unsigned inc = 1u << ((mi & 3) * 8);                    \
                const int r = mi >> 2;                                        \
                hc[0] += (r == 0) ? inc : 0u;                                 \
                hc[1] += (r == 1) ? inc : 0u;                                 \
                hc[2] += (r == 2) ? inc : 0u;                                 \
                hc[3] += (r == 3) ? inc : 0u;                                 \
                hc[4] += (r == 4) ? inc : 0u;                                 \
            }                                                                 \
            const float ml = m * L2E;                                         \
            float e[NC]; float d = 0.f;                                       \
            _Pragma("unroll")                                                 \
            for (int c = 0; c < NC; ++c) {                                    \
                e[c] = exp2f(fmaf(X[c], L2E, -ml));                           \
                d += e[c];                                                    \
            }                                                                 \
            const float inv  = __builtin_amdgcn_rcpf(d);                      \
            const float inv2 = inv * inv;                                     \
            _Pragma("unroll")                                                 \
            for (int c = 0; c < NC; ++c)                                      \
                acc[c] = fmaf(e[c] * e[c], inv2, acc[c]);                     \
        }

        PIXEL(x0); PIXEL(x1);
#undef PIXEL
    }

    // ---- unpack hist, wave (64-lane) butterfly reduce ----
    unsigned hu[NC];
#pragma unroll
    for (int c = 0; c < NC; ++c) hu[c] = (hc[c >> 2] >> ((c & 3) * 8)) & 0xFFu;

#pragma unroll
    for (int c = 0; c < NC; ++c) {
#pragma unroll
        for (int off = 32; off >= 1; off >>= 1) {
            acc[c] += __shfl_xor(acc[c], off, 64);
            hu[c]  += (unsigned)__shfl_xor((int)hu[c], off, 64);
        }
    }

    // ---- cross-wave combine via LDS (4 waves/block), deterministic ----
    __shared__ float    ls[TPB / 64][NC];
    __shared__ unsigned lh[TPB / 64][NC];
    const int wave = tid >> 6;
    const int lane = tid & 63;
    if (lane == 0) {
#pragma unroll
        for (int c = 0; c < NC; ++c) { ls[wave][c] = acc[c]; lh[wave][c] = hu[c]; }
    }
    __syncthreads();
    if (tid < NC) {
        float s = 0.f; unsigned h = 0u;
#pragma unroll
        for (int w = 0; w < TPB / 64; ++w) { s += ls[w][tid]; h += lh[w][tid]; }
        sPart[(size_t)b * NC + tid] = s;
        hPart[(size_t)b * NC + tid] = h;
    }
}

// ---------------- final reduce: block partials -> hist -> weight -> scalar loss ----------------
__global__ __launch_bounds__(1024) void iw_final(const float* __restrict__ sPart,
                                                 const unsigned* __restrict__ hPart,
                                                 float* __restrict__ out) {
    __shared__ double   ps[NIMG * NC][4];
    __shared__ unsigned ph[NIMG * NC][4];
    __shared__ double contrib[NIMG * NC];
    __shared__ double histL[NIMG * NC];
    __shared__ double hsum[NIMG];
    const int t   = threadIdx.x;
    const int idx = t >> 2;        // (n,c) pair
    const int k   = t & 3;

    if (idx < NIMG * NC) {
        const int n = idx / NC, c = idx % NC;
        double s = 0.0; unsigned h = 0u;
        for (int j = k; j < BPI; j += 4) {
            s += (double)sPart[(size_t)(n * BPI + j) * NC + c];
            h += hPart[(size_t)(n * BPI + j) * NC + c];
        }
        ps[idx][k] = s; ph[idx][k] = h;
    }
    __syncthreads();
    if (t < NIMG * NC) {
        double s = ps[t][0] + ps[t][1] + ps[t][2] + ps[t][3];
        unsigned h = ph[t][0] + ph[t][1] + ph[t][2] + ph[t][3];
        const double H = (h == 0u) ? 1.0 : (double)h;
        histL[t] = H;
        contrib[t] = s;              // temporarily S
    }
    __syncthreads();
    if (t < NIMG) {
        double hs = 0.0;
        for (int c = 0; c < NC; ++c) hs += histL[t * NC + c];
        hsum[t] = hs;
    }
    __syncthreads();
    if (t < NIMG * NC) {
        const int n = t / NC, c = t % NC;
        const double w = (c < OLD_CL) ? 1.0 : pow(hsum[n] / histL[t], 0.2);
        contrib[t] = w * contrib[t];
    }
    __syncthreads();
    if (t == 0) {
        double tot = 0.0;
        for (int i = 0; i < NIMG * NC; ++i) tot += contrib[i];
        out[0] = (float)(-tot / (double)((size_t)NIMG * NC * HW));
    }
}

extern "C" void kernel_launch(void* const* d_in, const int* in_sizes, int n_in,
                              void* d_out, int out_size, void* d_ws, size_t ws_size,
                              hipStream_t stream) {
    const float* in = (const float*)d_in[0];
    float* out = (float*)d_out;

    float*    sPart = (float*)d_ws;
    unsigned* hPart = (unsigned*)((char*)d_ws + (size_t)NIMG * BPI * NC * sizeof(float));

    iw_main<<<dim3(NIMG * BPI), TPB, 0, stream>>>(in, sPart, hPart);
    iw_final<<<1, 1024, 0, stream>>>(sPart, hPart, out);
}

// Round 4
// 67.971 us; speedup vs baseline: 1.4957x; 1.0729x over previous
//
#include <hip/hip_runtime.h>

#define NIMG 8
#define NC 19
#define HW (512*1024)
#define BPI 128          // blocks per image
#define TPB 256
#define ITERS 8          // float2 chunks/thread: (HW/2)/(BPI*TPB) = 262144/32768
#define CPB (ITERS*TPB)  // float2 chunks per block = 2048 (16KB/plane contiguous)
#define OLD_CL 11

typedef float    f32x2 __attribute__((ext_vector_type(2)));
typedef unsigned u32x2 __attribute__((ext_vector_type(2)));

// ---------------- main pass: per-pixel softmax^2 per-class sums + argmax hist ----------------
// Partials written TRANSPOSED: sPart[c][n][bl], hPart[c][n][bl]  (c*NIMG*BPI + n*BPI + bl)
__global__ __launch_bounds__(TPB, 4) void iw_main(const float* __restrict__ in,
                                                  float* __restrict__ sPart,
                                                  unsigned* __restrict__ hPart) {
    const int b   = blockIdx.x;        // 0 .. NIMG*BPI-1
    const int n   = b >> 7;            // image (BPI=128)
    const int bl  = b & (BPI - 1);
    const int tid = threadIdx.x;
    const float* img = in + (size_t)n * NC * HW;

    float    acc[NC];
    unsigned hc[5];                    // 19 counters x 8-bit fields (max 16 px/thread)
#pragma unroll
    for (int c = 0; c < NC; ++c) acc[c] = 0.f;
#pragma unroll
    for (int r = 0; r < 5; ++r) hc[r] = 0u;

    const float L2E = 1.4426950408889634f;

    for (int it = 0; it < ITERS; ++it) {
        // contiguous per-block mapping: block streams 16KB/plane sequentially
        const int    chunk = bl * CPB + it * TPB + tid;
        const size_t p     = (size_t)chunk * 2;

        float x0[NC], x1[NC];
#pragma unroll
        for (int c = 0; c < NC; ++c) {
            const f32x2 t = __builtin_nontemporal_load(
                reinterpret_cast<const f32x2*>(img + (size_t)c * HW + p));
            x0[c] = t[0]; x1[c] = t[1];
        }

#define PIXEL(X)                                                              \
        {                                                                     \
            float m = X[0];                                                   \
            _Pragma("unroll")                                                 \
            for (int c = 1; c < NC; ++c) m = fmaxf(m, X[c]);                  \
            int mi = NC - 1;                                                  \
            _Pragma("unroll")                                                 \
            for (int c = NC - 2; c >= 0; --c) mi = (X[c] == m) ? c : mi;      \
            {                                                                 \
                const unsigned inc = 1u << ((mi & 3) * 8);                    \
                const int r = mi >> 2;                                        \
                hc[0] += (r == 0) ? inc : 0u;                                 \
                hc[1] += (r == 1) ? inc : 0u;                                 \
                hc[2] += (r == 2) ? inc : 0u;                                 \
                hc[3] += (r == 3) ? inc : 0u;                                 \
                hc[4] += (r == 4) ? inc : 0u;                                 \
            }                                                                 \
            const float ml = m * L2E;                                         \
            float e[NC]; float d = 0.f;                                       \
            _Pragma("unroll")                                                 \
            for (int c = 0; c < NC; ++c) {                                    \
                e[c] = exp2f(fmaf(X[c], L2E, -ml));                           \
                d += e[c];                                                    \
            }                                                                 \
            const float inv  = __builtin_amdgcn_rcpf(d);                      \
            const float inv2 = inv * inv;                                     \
            _Pragma("unroll")                                                 \
            for (int c = 0; c < NC; ++c)                                      \
                acc[c] = fmaf(e[c] * e[c], inv2, acc[c]);                     \
        }

        PIXEL(x0); PIXEL(x1);
#undef PIXEL
    }

    // ---- unpack hist, wave (64-lane) butterfly reduce ----
    unsigned hu[NC];
#pragma unroll
    for (int c = 0; c < NC; ++c) hu[c] = (hc[c >> 2] >> ((c & 3) * 8)) & 0xFFu;

#pragma unroll
    for (int c = 0; c < NC; ++c) {
#pragma unroll
        for (int off = 32; off >= 1; off >>= 1) {
            acc[c] += __shfl_xor(acc[c], off, 64);
            hu[c]  += (unsigned)__shfl_xor((int)hu[c], off, 64);
        }
    }

    // ---- cross-wave combine via LDS (4 waves/block), deterministic ----
    __shared__ float    ls[TPB / 64][NC];
    __shared__ unsigned lh[TPB / 64][NC];
    const int wave = tid >> 6;
    const int lane = tid & 63;
    if (lane == 0) {
#pragma unroll
        for (int c = 0; c < NC; ++c) { ls[wave][c] = acc[c]; lh[wave][c] = hu[c]; }
    }
    __syncthreads();
    if (tid < NC) {
        float s = 0.f; unsigned h = 0u;
#pragma unroll
        for (int w = 0; w < TPB / 64; ++w) { s += ls[w][tid]; h += lh[w][tid]; }
        // transposed: [c][n][bl]
        sPart[(size_t)tid * (NIMG * BPI) + n * BPI + bl] = s;
        hPart[(size_t)tid * (NIMG * BPI) + n * BPI + bl] = h;
    }
}

// ---------------- final reduce: coalesced wave-parallel partial reduce -> weight -> loss ----------------
__global__ __launch_bounds__(1024) void iw_final(const float* __restrict__ sPart,
                                                 const unsigned* __restrict__ hPart,
                                                 float* __restrict__ out) {
    __shared__ float    sRed[NIMG * NC];
    __shared__ unsigned hRed[NIMG * NC];
    __shared__ double contrib[NIMG * NC];
    __shared__ double histL[NIMG * NC];
    __shared__ double hsum[NIMG];

    const int t    = threadIdx.x;
    const int wv   = t >> 6;           // 16 waves
    const int lane = t & 63;

    // each wave handles pairs wv, wv+16, wv+32, ... (10 slots, 152 pairs total)
    f32x2 ps[10]; u32x2 ph[10];
#pragma unroll
    for (int i = 0; i < 10; ++i) {
        const int pair = wv + 16 * i;
        if (pair < NIMG * NC) {
            // pair = c*NIMG + n?  No: iterate pair as linear over [c][n]
            const size_t base = (size_t)pair * BPI + lane * 2;
            ps[i] = *reinterpret_cast<const f32x2*>(sPart + base);
            ph[i] = *reinterpret_cast<const u32x2*>(hPart + base);
        }
    }
#pragma unroll
    for (int i = 0; i < 10; ++i) {
        const int pair = wv + 16 * i;
        if (pair < NIMG * NC) {
            float    s = ps[i][0] + ps[i][1];
            unsigned h = ph[i][0] + ph[i][1];
#pragma unroll
            for (int off = 32; off >= 1; off >>= 1) {
                s += __shfl_xor(s, off, 64);
                h += (unsigned)__shfl_xor((int)h, off, 64);
            }
            if (lane == 0) { sRed[pair] = s; hRed[pair] = h; }
        }
    }
    __syncthreads();

    // pair index is [c][n] linear; convert to (n,c)
    if (t < NIMG * NC) {
        const int c = t / NIMG, n = t % NIMG;
        const int idx = n * NC + c;                  // canonical (n,c)
        const unsigned h = hRed[t];
        histL[idx]  = (h == 0u) ? 1.0 : (double)h;
        contrib[idx] = (double)sRed[t];              // temporarily S
    }
    __syncthreads();
    if (t < NIMG) {
        double hs = 0.0;
        for (int c = 0; c < NC; ++c) hs += histL[t * NC + c];
        hsum[t] = hs;
    }
    __syncthreads();
    if (t < NIMG * NC) {
        const int n = t / NC, c = t % NC;
        const double w = (c < OLD_CL) ? 1.0 : pow(hsum[n] / histL[t], 0.2);
        contrib[t] = w * contrib[t];
    }
    __syncthreads();
    if (t == 0) {
        double tot = 0.0;
        for (int i = 0; i < NIMG * NC; ++i) tot += contrib[i];
        out[0] = (float)(-tot / (double)((size_t)NIMG * NC * HW));
    }
}

extern "C" void kernel_launch(void* const* d_in, const int* in_sizes, int n_in,
                              void* d_out, int out_size, void* d_ws, size_t ws_size,
                              hipStream_t stream) {
    const float* in = (const float*)d_in[0];
    float* out = (float*)d_out;

    float*    sPart = (float*)d_ws;
    unsigned* hPart = (unsigned*)((char*)d_ws + (size_t)NC * NIMG * BPI * sizeof(float));

    iw_main<<<dim3(NIMG * BPI), TPB, 0, stream>>>(in, sPart, hPart);
    iw_final<<<1, 1024, 0, stream>>>(sPart, hPart, out);
}